// Round 9
// baseline (512.204 us; speedup 1.0000x reference)
//
#include <hip/hip_runtime.h>
#include <stdint.h>
#include <stddef.h>

typedef __bf16 bf16_t;
typedef __bf16 bf16x8 __attribute__((ext_vector_type(8)));
typedef __bf16 bf16x4 __attribute__((ext_vector_type(4)));
typedef __bf16 bf16x2 __attribute__((ext_vector_type(2)));
typedef float  f32x4  __attribute__((ext_vector_type(4)));

#define SEQ   3072
#define DIMD  2048
#define NH    16
#define HD    128
#define QKVN  6144

__device__ __forceinline__ void async16(const bf16_t* g, bf16_t* l) {
  __builtin_amdgcn_global_load_lds((const __attribute__((address_space(1))) uint32_t*)g,
                                   (__attribute__((address_space(3))) uint32_t*)l, 16, 0, 0);
}

// ---------------- fused converts + bias pack (one launch) ----------------
__global__ __launch_bounds__(256) void cvt_all(const float* __restrict__ x,
                                               const float* __restrict__ Wq,
                                               const float* __restrict__ Wk,
                                               const float* __restrict__ Wv,
                                               const float* __restrict__ Wo,
                                               const float* __restrict__ bq,
                                               const float* __restrict__ bk,
                                               const float* __restrict__ bv,
                                               bf16_t* __restrict__ xb,
                                               bf16_t* __restrict__ Wqkvb,
                                               bf16_t* __restrict__ Wob,
                                               float* __restrict__ bqkv) {
  const int b = blockIdx.x;
  const float* src; bf16_t* dst; int off;
  if (b < 3072)       { src = x;  dst = xb;              off = b; }
  else if (b < 5120)  { src = Wq; dst = Wqkvb;           off = b - 3072; }
  else if (b < 7168)  { src = Wk; dst = Wqkvb + 4194304; off = b - 5120; }
  else if (b < 9216)  { src = Wv; dst = Wqkvb + 8388608; off = b - 7168; }
  else if (b < 11264) { src = Wo; dst = Wob;             off = b - 9216; }
  else {  // bias pack: 24 blocks cover 6144
    int t = (b - 11264) * 256 + threadIdx.x;
    float v;
    if (t < 2048)      v = bq[t];
    else if (t < 4096) v = bk[t - 2048];
    else               v = bv[t - 4096];
    bqkv[t] = v;
    return;
  }
  const int idx = (off * 256 + threadIdx.x) * 8;
  const float4 a = *(const float4*)(src + idx);
  const float4 c = *(const float4*)(src + idx + 4);
  bf16x8 o;
  o[0] = (bf16_t)a.x; o[1] = (bf16_t)a.y; o[2] = (bf16_t)a.z; o[3] = (bf16_t)a.w;
  o[4] = (bf16_t)c.x; o[5] = (bf16_t)c.y; o[6] = (bf16_t)c.z; o[7] = (bf16_t)c.w;
  *(bf16x8*)(dst + idx) = o;
}

// ---------------- GEMM: C[M,N] = A[M,K] * B[N,K]^T + bias ----------------
template<bool OUT_BF16>
__global__ __launch_bounds__(256, 3) void gemm_nt(const bf16_t* __restrict__ A,
                                                  const bf16_t* __restrict__ B,
                                                  const float* __restrict__ bias,
                                                  void* __restrict__ Cout,
                                                  int M, int N, int K) {
  __shared__ __align__(16) bf16_t As[128 * 64];
  __shared__ __align__(16) bf16_t Bs[128 * 64];
  const int t = threadIdx.x;
  const int lane = t & 63, wave = t >> 6;
  const int quad = lane >> 4, l15 = lane & 15;
  const int wy = wave >> 1, wx = wave & 1;
  const size_t bm = (size_t)blockIdx.y * 128, bn = (size_t)blockIdx.x * 128;
  const bf16_t* Ab = A + bm * K;
  const bf16_t* Bb = B + bn * K;
  f32x4 acc[4][4] = {};
  int srow[4], scol[4];
#pragma unroll
  for (int r = 0; r < 4; r++) {
    int L = r * 256 + t;
    int row = L >> 3, cp = L & 7;
    srow[r] = row;
    scol[r] = (cp ^ (row & 7)) * 8;
  }
  for (int k0 = 0; k0 < K; k0 += 64) {
    __syncthreads();
#pragma unroll
    for (int r = 0; r < 4; r++)
      async16(Ab + (size_t)srow[r] * K + k0 + scol[r], &As[(r * 256 + t) * 8]);
#pragma unroll
    for (int r = 0; r < 4; r++)
      async16(Bb + (size_t)srow[r] * K + k0 + scol[r], &Bs[(r * 256 + t) * 8]);
    __syncthreads();
#pragma unroll
    for (int ks = 0; ks < 2; ks++) {
      bf16x8 af[4], bfv[4];
#pragma unroll
      for (int i = 0; i < 4; i++) {
        int row = wy * 64 + i * 16 + l15;
        af[i] = *(const bf16x8*)&As[row * 64 + (((ks * 4 + quad) ^ (row & 7)) * 8)];
      }
#pragma unroll
      for (int j = 0; j < 4; j++) {
        int row = wx * 64 + j * 16 + l15;
        bfv[j] = *(const bf16x8*)&Bs[row * 64 + (((ks * 4 + quad) ^ (row & 7)) * 8)];
      }
#pragma unroll
      for (int i = 0; i < 4; i++)
#pragma unroll
        for (int j = 0; j < 4; j++)
          acc[i][j] = __builtin_amdgcn_mfma_f32_16x16x32_bf16(af[i], bfv[j], acc[i][j], 0, 0, 0);
    }
  }
#pragma unroll
  for (int i = 0; i < 4; i++) {
#pragma unroll
    for (int j = 0; j < 4; j++) {
      size_t row = bm + wy * 64 + i * 16 + quad * 4;
      size_t col = bn + wx * 64 + j * 16 + l15;
      float bb = bias[col];
#pragma unroll
      for (int r = 0; r < 4; r++) {
        float v = acc[i][j][r] + bb;
        if (OUT_BF16) ((bf16_t*)Cout)[(row + r) * N + col] = (bf16_t)v;
        else          ((float*)Cout)[(row + r) * N + col] = v;
      }
    }
  }
}

// ---------------- GEMM variant: 128x64 tile (N=2048 -> 768 blocks = 3/CU) ----------
template<bool OUT_BF16>
__global__ __launch_bounds__(256, 3) void gemm_nt64(const bf16_t* __restrict__ A,
                                                    const bf16_t* __restrict__ B,
                                                    const float* __restrict__ bias,
                                                    void* __restrict__ Cout,
                                                    int M, int N, int K) {
  __shared__ __align__(16) bf16_t As[128 * 64];  // 16 KB
  __shared__ __align__(16) bf16_t Bs[64 * 64];   //  8 KB
  const int t = threadIdx.x;
  const int lane = t & 63, wave = t >> 6;
  const int quad = lane >> 4, l15 = lane & 15;
  const int wy = wave >> 1, wx = wave & 1;
  const size_t bm = (size_t)blockIdx.y * 128, bn = (size_t)blockIdx.x * 64;
  const bf16_t* Ab = A + bm * K;
  const bf16_t* Bb = B + bn * K;
  f32x4 acc[4][2] = {};
  for (int k0 = 0; k0 < K; k0 += 64) {
    __syncthreads();
#pragma unroll
    for (int r = 0; r < 4; r++) {
      int L = r * 256 + t, row = L >> 3, cp = L & 7;
      async16(Ab + (size_t)row * K + k0 + (cp ^ (row & 7)) * 8, &As[L * 8]);
    }
#pragma unroll
    for (int r = 0; r < 2; r++) {
      int L = r * 256 + t, row = L >> 3, cp = L & 7;
      async16(Bb + (size_t)row * K + k0 + (cp ^ (row & 7)) * 8, &Bs[L * 8]);
    }
    __syncthreads();
#pragma unroll
    for (int ks = 0; ks < 2; ks++) {
      bf16x8 af[4], bfv[2];
#pragma unroll
      for (int i = 0; i < 4; i++) {
        int row = wy * 64 + i * 16 + l15;
        af[i] = *(const bf16x8*)&As[row * 64 + (((ks * 4 + quad) ^ (row & 7)) * 8)];
      }
#pragma unroll
      for (int j = 0; j < 2; j++) {
        int row = wx * 32 + j * 16 + l15;
        bfv[j] = *(const bf16x8*)&Bs[row * 64 + (((ks * 4 + quad) ^ (row & 7)) * 8)];
      }
#pragma unroll
      for (int i = 0; i < 4; i++)
#pragma unroll
        for (int j = 0; j < 2; j++)
          acc[i][j] = __builtin_amdgcn_mfma_f32_16x16x32_bf16(af[i], bfv[j], acc[i][j], 0, 0, 0);
    }
  }
#pragma unroll
  for (int i = 0; i < 4; i++) {
#pragma unroll
    for (int j = 0; j < 2; j++) {
      size_t row = bm + wy * 64 + i * 16 + quad * 4;
      size_t col = bn + wx * 32 + j * 16 + l15;
      float bb = bias[col];
#pragma unroll
      for (int r = 0; r < 4; r++) {
        float v = acc[i][j][r] + bb;
        if (OUT_BF16) ((bf16_t*)Cout)[(row + r) * N + col] = (bf16_t)v;
        else          ((float*)Cout)[(row + r) * N + col] = v;
      }
    }
  }
}

// ---------------- prep: RMS+RoPE (blocks 0..3071) + V transpose (3072..3839) -------
// Independent work on disjoint qkv columns -> safe in one launch.
__global__ __launch_bounds__(256) void prep(bf16_t* __restrict__ qkv,
                                            bf16_t* __restrict__ pk,
                                            bf16_t* __restrict__ pvt,
                                            const float* __restrict__ gq,
                                            const float* __restrict__ gk,
                                            const float* __restrict__ freqs) {
  __shared__ bf16_t tile[128][65];   // vtrans path (rms path uses first 32 B)
  const int t = threadIdx.x;
  if (blockIdx.x >= 3072) {
    const int vb = blockIdx.x - 3072;       // 0..767
    const int h = vb / 48;
    const int s0 = (vb - h * 48) * 64;
#pragma unroll
    for (int r = 0; r < 4; r++) {
      int L = r * 256 + t, s = L >> 4, cp = L & 15;
      bf16x8 v = *(const bf16x8*)&qkv[(size_t)(s0 + s) * QKVN + 4096 + h * HD + cp * 8];
#pragma unroll
      for (int i = 0; i < 8; i++) tile[cp * 8 + i][s] = v[i];
    }
    __syncthreads();
#pragma unroll
    for (int r = 0; r < 4; r++) {
      int L = r * 256 + t, d = L >> 3, c = L & 7;
      bf16x8 o;
#pragma unroll
      for (int i = 0; i < 8; i++) o[i] = tile[d][c * 8 + i];
      *(bf16x8*)&pvt[((size_t)h * HD + d) * SEQ + s0 + c * 8] = o;
    }
    return;
  }
  const int s = blockIdx.x;
  const float SC2 = 0.08838834764831845f * 1.44269504088896f;  // 1/sqrt(128) * log2(e)
  bf16_t* row = qkv + (size_t)s * QKVN;
  bf16x8 qv = *(const bf16x8*)&row[t * 8];
  bf16x8 kv = *(const bf16x8*)&row[2048 + t * 8];
  float qf[8], kf[8];
  float qs = 0.f, ks2 = 0.f;
#pragma unroll
  for (int i = 0; i < 8; i++) {
    qf[i] = (float)qv[i]; qs  += qf[i] * qf[i];
    kf[i] = (float)kv[i]; ks2 += kf[i] * kf[i];
  }
#pragma unroll
  for (int m = 1; m < 64; m <<= 1) {
    qs  += __shfl_xor(qs, m);
    ks2 += __shfl_xor(ks2, m);
  }
  __shared__ float red[2][4];
  const int wave = t >> 6, lane = t & 63;
  if (lane == 0) { red[0][wave] = qs; red[1][wave] = ks2; }
  __syncthreads();
  qs  = red[0][0] + red[0][1] + red[0][2] + red[0][3];
  ks2 = red[1][0] + red[1][1] + red[1][2] + red[1][3];
  const float qsc = rsqrtf(qs  / 2048.f + 1e-6f) * SC2;
  const float ksc = rsqrtf(ks2 / 2048.f + 1e-6f);
  const int sf = s / 384, rem = s - sf * 384;
  const int sh = rem / 24, sw = rem - sh * 24;
  bf16x8 qo, ko;
#pragma unroll
  for (int u = 0; u < 4; u++) {
    const int col = t * 8 + 2 * u;
    const int i = (col >> 1) & 63;                         // pair index within head (c=64)
    const int frow = (i < 22) ? sf : ((i < 43) ? sh : sw); // cf=22, ch=cw=21
    const float ang = freqs[frow * 64 + i];
    float sn, cs;
    __sincosf(ang, &sn, &cs);
    float te = qf[2 * u]     * qsc * gq[col];
    float to = qf[2 * u + 1] * qsc * gq[col + 1];
    qo[2 * u]     = (bf16_t)(te * cs - to * sn);
    qo[2 * u + 1] = (bf16_t)(te * sn + to * cs);
    te = kf[2 * u]     * ksc * gk[col];
    to = kf[2 * u + 1] * ksc * gk[col + 1];
    ko[2 * u]     = (bf16_t)(te * cs - to * sn);
    ko[2 * u + 1] = (bf16_t)(te * sn + to * cs);
  }
  *(bf16x8*)&row[t * 8] = qo;
  *(bf16x8*)&pk[((size_t)(t >> 4) * SEQ + s) * HD + (t & 15) * 8] = ko;
}

// ---------------- Flash attention: 2 fat waves x 64 q rows, q-tile 128 ----------------
// Grid dim3(24,16), 128 threads. Per-wave LDS operand traffic (full K+V tile per wave)
// is fixed, so fewer/fatter waves cut total LDS traffic 33%. launch_bounds(128,1):
// ~340 live VGPRs, 1 wave/SIMD — ILP from 16 independent QK chains replaces TLP.
__global__ __launch_bounds__(128, 1) void flash_attn(const bf16_t* __restrict__ qkv,
                                                     const bf16_t* __restrict__ pk,
                                                     const bf16_t* __restrict__ pvt,
                                                     bf16_t* __restrict__ ob) {
  __shared__ __align__(16) bf16_t Ks[2][64 * 128];  // [kv][d], xor-swizzled chunks
  __shared__ __align__(16) bf16_t Vt[2][128 * 64];  // [d][kv], xor-swizzled chunks
  __shared__ __align__(16) bf16_t Ps[2][64 * 64];   // per-wave P [q][kv], swizzled
  const int h = blockIdx.y, qt = blockIdx.x;
  const int s0 = qt * 128;
  const int t = threadIdx.x, wave = t >> 6, lane = t & 63;
  const int quad = lane >> 4, l15 = lane & 15;
  const int wq = wave * 64;
  const bf16_t* pkh = pk  + (size_t)h * (SEQ * HD);
  const bf16_t* pvh = pvt + (size_t)h * (HD * SEQ);
  // staging offsets: 1024 K-chunks + 1024 V-chunks over 128 threads (8 each)
  int koff[8], voff[8];
#pragma unroll
  for (int r = 0; r < 8; r++) {
    int L = r * 128 + t;
    int krow = L >> 4, kc = (L & 15) ^ (krow & 7);
    koff[r] = krow * HD + kc * 8;
    int vd = L >> 3, vc = (L & 7) ^ (vd & 7);
    voff[r] = vd * SEQ + vc * 8;
  }
  bf16x8 qfr[4][4];
#pragma unroll
  for (int tj = 0; tj < 4; tj++)
#pragma unroll
    for (int ks = 0; ks < 4; ks++)
      qfr[tj][ks] = *(const bf16x8*)&qkv[(size_t)(s0 + wq + tj * 16 + l15) * QKVN + h * HD + ks * 32 + quad * 8];
  bf16x8 onesf;
#pragma unroll
  for (int i = 0; i < 8; i++) onesf[i] = (bf16_t)1.0f;
  f32x4 oacc[4][8] = {};
  f32x4 lacc[4] = {};
  float m_run[4] = {-3e38f, -3e38f, -3e38f, -3e38f};
  // preload tile 0 into buffer 0
#pragma unroll
  for (int r = 0; r < 8; r++)
    async16(pkh + koff[r], &Ks[0][(r * 128 + t) * 8]);
#pragma unroll
  for (int r = 0; r < 8; r++)
    async16(pvh + voff[r], &Vt[0][(r * 128 + t) * 8]);
  for (int kt = 0; kt < SEQ / 64; kt++) {
    const int cur = kt & 1;
    __syncthreads();  // tile kt landed; all waves done reading buf cur^1
    if (kt + 1 < SEQ / 64) {
      const int kv1 = (kt + 1) * 64;
#pragma unroll
      for (int r = 0; r < 8; r++)
        async16(pkh + (size_t)kv1 * HD + koff[r], &Ks[cur ^ 1][(r * 128 + t) * 8]);
#pragma unroll
      for (int r = 0; r < 8; r++)
        async16(pvh + kv1 + voff[r], &Vt[cur ^ 1][(r * 128 + t) * 8]);
    }
    // S^T = K * Q^T -> lane holds S^T[kv=ti*16+quad*4+r][q=tj*16+l15], exp2 domain
    f32x4 st[4][4] = {};
#pragma unroll
    for (int ks = 0; ks < 4; ks++) {
      bf16x8 kfr[4];
#pragma unroll
      for (int ti = 0; ti < 4; ti++) {
        const int kr = ti * 16 + l15;
        kfr[ti] = *(const bf16x8*)&Ks[cur][kr * 128 + (((ks * 4 + quad) ^ (kr & 7)) * 8)];
      }
#pragma unroll
      for (int ti = 0; ti < 4; ti++)
#pragma unroll
        for (int tj = 0; tj < 4; tj++)
          st[ti][tj] = __builtin_amdgcn_mfma_f32_16x16x32_bf16(kfr[ti], qfr[tj][ks], st[ti][tj], 0, 0, 0);
    }
    // online softmax over kv (column reduction of S^T = across quads)
    float mt[4] = {-3e38f, -3e38f, -3e38f, -3e38f};
#pragma unroll
    for (int ti = 0; ti < 4; ti++)
#pragma unroll
      for (int tj = 0; tj < 4; tj++)
#pragma unroll
        for (int r = 0; r < 4; r++)
          mt[tj] = fmaxf(mt[tj], st[ti][tj][r]);
    float al[4];
#pragma unroll
    for (int tj = 0; tj < 4; tj++) {
      mt[tj] = fmaxf(mt[tj], __shfl_xor(mt[tj], 16));
      mt[tj] = fmaxf(mt[tj], __shfl_xor(mt[tj], 32));
      const float mn = fmaxf(m_run[tj], mt[tj]);
      al[tj] = exp2f(m_run[tj] - mn);
      m_run[tj] = mn;
    }
#pragma unroll
    for (int ti = 0; ti < 4; ti++)
#pragma unroll
      for (int tj = 0; tj < 4; tj++) {
        bf16x4 pv;
#pragma unroll
        for (int r = 0; r < 4; r++)
          pv[r] = (bf16_t)exp2f(st[ti][tj][r] - m_run[tj]);
        const int q = tj * 16 + l15;
        const int cp2 = (ti * 2 + (quad >> 1)) ^ (q & 7);
        *(bf16x4*)&Ps[wave][q * 64 + cp2 * 8 + (quad & 1) * 4] = pv;
      }
    // rescale O and l accumulators only when some alpha != 1 (exact skip)
    if (__ballot((al[0] != 1.f) | (al[1] != 1.f) | (al[2] != 1.f) | (al[3] != 1.f))) {
#pragma unroll
      for (int tq = 0; tq < 4; tq++) {
        float a0 = __shfl(al[tq], quad * 4 + 0);
        float a1 = __shfl(al[tq], quad * 4 + 1);
        float a2 = __shfl(al[tq], quad * 4 + 2);
        float a3 = __shfl(al[tq], quad * 4 + 3);
        lacc[tq][0] *= a0; lacc[tq][1] *= a1;
        lacc[tq][2] *= a2; lacc[tq][3] *= a3;
#pragma unroll
        for (int dj = 0; dj < 8; dj++) {
          oacc[tq][dj][0] *= a0; oacc[tq][dj][1] *= a1;
          oacc[tq][dj][2] *= a2; oacc[tq][dj][3] *= a3;
        }
      }
    }
    // O += P * V ;  l += P * 1 (ones-MFMA, C-layout rows q=quad*4+r)
#pragma unroll
    for (int ks = 0; ks < 2; ks++) {
      bf16x8 pf[4], vf[8];
#pragma unroll
      for (int tq = 0; tq < 4; tq++) {
        const int q = tq * 16 + l15;
        pf[tq] = *(const bf16x8*)&Ps[wave][q * 64 + (((ks * 4 + quad) ^ (q & 7)) * 8)];
      }
#pragma unroll
      for (int dj = 0; dj < 8; dj++) {
        const int d = dj * 16 + l15;
        vf[dj] = *(const bf16x8*)&Vt[cur][d * 64 + (((ks * 4 + quad) ^ (d & 7)) * 8)];
      }
#pragma unroll
      for (int tq = 0; tq < 4; tq++) {
        lacc[tq] = __builtin_amdgcn_mfma_f32_16x16x32_bf16(pf[tq], onesf, lacc[tq], 0, 0, 0);
#pragma unroll
        for (int dj = 0; dj < 8; dj++)
          oacc[tq][dj] = __builtin_amdgcn_mfma_f32_16x16x32_bf16(pf[tq], vf[dj], oacc[tq][dj], 0, 0, 0);
      }
    }
  }
  // epilogue: divide by l (lacc rows already q=quad*4+r), store bf16
#pragma unroll
  for (int tq = 0; tq < 4; tq++) {
    float li[4];
#pragma unroll
    for (int r = 0; r < 4; r++) li[r] = 1.f / lacc[tq][r];
#pragma unroll
    for (int dj = 0; dj < 8; dj++)
#pragma unroll
      for (int r = 0; r < 4; r++) {
        const float v = oacc[tq][dj][r] * li[r];
        ob[(size_t)(s0 + wq + tq * 16 + quad * 4 + r) * DIMD + h * HD + dj * 16 + l15] = (bf16_t)v;
      }
  }
}

// ---------------- launch ----------------
extern "C" void kernel_launch(void* const* d_in, const int* in_sizes, int n_in,
                              void* d_out, int out_size, void* d_ws, size_t ws_size,
                              hipStream_t stream) {
  (void)in_sizes; (void)n_in; (void)out_size;
  const float* x     = (const float*)d_in[0];
  const float* freqs = (const float*)d_in[1];
  const float* Wq    = (const float*)d_in[2];
  const float* bq    = (const float*)d_in[3];
  const float* Wk    = (const float*)d_in[4];
  const float* bk    = (const float*)d_in[5];
  const float* Wv    = (const float*)d_in[6];
  const float* bv    = (const float*)d_in[7];
  const float* Wo    = (const float*)d_in[8];
  const float* bo    = (const float*)d_in[9];
  const float* gq    = (const float*)d_in[10];
  const float* gk    = (const float*)d_in[11];

  // workspace carve (bytes); [0, 37748736) holds xb+Wqkvb during gemm1,
  // reused afterwards for pk / pvt.
  char* w = (char*)d_ws;
  bf16_t* xb    = (bf16_t*)(w);                 // x bf16:        12,582,912 B
  bf16_t* Wqkvb = (bf16_t*)(w + 12582912);      // Wq|Wk|Wv bf16: 25,165,824 B
  bf16_t* Wob   = (bf16_t*)(w + 37748736);      // Wo bf16:        8,388,608 B
  bf16_t* qkvb  = (bf16_t*)(w + 46137344);      // qkv bf16:      37,748,736 B
  bf16_t* obuf  = (bf16_t*)(w + 83886080);      // attn out bf16: 12,582,912 B
  float*  bqkv  = (float*) (w + 96468992);      // stacked bias:      24,576 B
  bf16_t* pk    = (bf16_t*)(w);                 // K packed [16][3072][128]: 12,582,912 B
  bf16_t* pvt   = (bf16_t*)(w + 12582912);      // V^T [16][128][3072]:      12,582,912 B
  if (ws_size < (size_t)96493568) return;

  // converts + bias pack (one launch)
  cvt_all<<<11288, 256, 0, stream>>>(x, Wq, Wk, Wv, Wo, bq, bk, bv, xb, Wqkvb, Wob, bqkv);

  // qkv = x @ [Wq;Wk;Wv]^T + bias   (3072 x 6144 x 2048)
  gemm_nt<true><<<dim3(48, 24), 256, 0, stream>>>(xb, Wqkvb, bqkv, qkvb, SEQ, QKVN, DIMD);
  // RMS+RoPE (q pre-scaled, k -> pk) + V transpose (-> pvt), one launch
  prep<<<3840, 256, 0, stream>>>(qkvb, pk, pvt, gq, gk, freqs);
  // attention (2 fat waves x 64 q, double-buffered, lean softmax) -> obuf
  flash_attn<<<dim3(24, NH), 128, 0, stream>>>(qkvb, pk, pvt, obuf);
  // out = obuf @ Wo^T + bo  (3072 x 2048 x 2048), fp32 out; 128x64 tile -> 768 blocks
  gemm_nt64<false><<<dim3(32, 24), 256, 0, stream>>>(obuf, Wob, bo, (float*)d_out, SEQ, DIMD, DIMD);
}